// Round 3
// baseline (83.285 us; speedup 1.0000x reference)
//
#include <hip/hip_runtime.h>

// Problem constants (fixed by setup_inputs in the reference):
//   candidate_pts (2,128,10,3) -> queries (B=2, S=1280, 3)
//   src_keypts    (2,128,3)    -> UNUSED by reference
//   tgt_pts_xyz   (2,16384,3)
//   tgt_deep_feat (2,16384,32)
// out (2,128,10,32,35) fp32 = (B, S, K=32, 3+F)
constexpr int B_  = 2;
constexpr int S_  = 1280;     // 128 * 10
constexpr int N_  = 16384;
constexpr int F_  = 32;
constexpr int K_  = 32;
constexpr int CH_ = 3 + F_;   // 35
constexpr float R2_ = 4.0f;   // D_RADIUS^2

constexpr int WPB    = 16;          // waves per block
constexpr int NCHUNK = N_ / 64;     // 256 chunks of 64 points
constexpr int NR     = NCHUNK / WPB;// 16 rounds; round r covers points [1024r, 1024(r+1))

// One block (16 waves) per query. Round-parallel scan with block-uniform
// early exit; wave 0 extracts the first K_ in-radius indices from the ballot
// words; all waves write the gathered output.
__global__ __launch_bounds__(1024) void ballquery_gather(
    const float* __restrict__ cand,   // (B,S,3)
    const float* __restrict__ xyz,    // (B,N,3)
    const float* __restrict__ feat,   // (B,N,F)
    float* __restrict__ out)          // (B,S,K,CH)
{
    const int q    = blockIdx.x;          // 0 .. B*S-1
    const int b    = q / S_;
    const int tid  = threadIdx.x;
    const int wave = tid >> 6;
    const int lane = tid & 63;

    const float qx = cand[q * 3 + 0];
    const float qy = cand[q * 3 + 1];
    const float qz = cand[q * 3 + 2];
    // Replicate reference op order exactly; _rn intrinsics forbid FMA fusion.
    const float qq = __fadd_rn(__fadd_rn(__fmul_rn(qx, qx), __fmul_rn(qy, qy)),
                               __fmul_rn(qz, qz));

    const float* __restrict__ xb = xyz  + (size_t)b * N_ * 3;
    const float* __restrict__ fb = feat + (size_t)b * N_ * F_;

    __shared__ unsigned long long ball[NCHUNK];          // ballot word per chunk
    __shared__ int  cnt[NCHUNK] __attribute__((aligned(16)));
    __shared__ int  sidx[K_];

    // ---- round-parallel scan with early exit ----
    float cx, cy, cz, nx, ny, nz;
    {   // preload round 0: chunk = wave
        const int n = wave * 64 + lane;
        cx = xb[n * 3 + 0]; cy = xb[n * 3 + 1]; cz = xb[n * 3 + 2];
    }

    int total   = 0;   // in-radius hits over scanned prefix (block-uniform)
    int scanned = 0;   // chunks scanned (block-uniform)
    for (int r = 0; r < NR; ++r) {
        // speculative preload for round r+1 (clamped: reload same chunk on last)
        const int rn = (r + 1 < NR) ? (r + 1) : r;
        const int nn_ = (rn * WPB + wave) * 64 + lane;
        nx = xb[nn_ * 3 + 0]; ny = xb[nn_ * 3 + 1]; nz = xb[nn_ * 3 + 2];

        // evaluate current chunk
        const float dot = __fadd_rn(__fadd_rn(__fmul_rn(qx, cx), __fmul_rn(qy, cy)),
                                    __fmul_rn(qz, cz));
        const float xx  = __fadd_rn(__fadd_rn(__fmul_rn(cx, cx), __fmul_rn(cy, cy)),
                                    __fmul_rn(cz, cz));
        // sqr = (qq - 2*dot) + xx   (matches  sum1 - 2*einsum + sum2)
        const float sqr = __fadd_rn(__fsub_rn(qq, __fmul_rn(2.0f, dot)), xx);
        const bool pred = !(sqr > R2_);   // kept iff sqr <= R2 (NaN-keeping)

        const unsigned long long m = __ballot(pred);
        const int c = r * WPB + wave;
        if (lane == 0) { ball[c] = m; cnt[c] = __popcll(m); }
        __syncthreads();

        // block-uniform running total via LDS broadcast reads
        int s = 0;
        const int4* cp = (const int4*)&cnt[r * WPB];
        #pragma unroll
        for (int j = 0; j < 4; ++j) { const int4 v = cp[j]; s += v.x + v.y + v.z + v.w; }
        total   += s;
        scanned += WPB;
        if (total >= K_) break;          // uniform across block

        cx = nx; cy = ny; cz = nz;
    }

    // ---- extraction: wave 0 finds the first K_ indices in ascending order ----
    if (wave == 0) {
        unsigned long long m[4];
        int t = 0;
        #pragma unroll
        for (int j = 0; j < 4; ++j) {
            const int c = 4 * lane + j;
            m[j] = (c < scanned) ? ball[c] : 0ull;
            t += __popcll(m[j]);
        }
        // exclusive prefix over 64 lanes
        int p = t;
        #pragma unroll
        for (int off = 1; off < 64; off <<= 1) {
            const int v = __shfl_up(p, off);
            if (lane >= off) p += v;
        }
        p -= t;
        int rank = p;
        #pragma unroll
        for (int j = 0; j < 4; ++j) {
            unsigned long long mm = m[j];
            while (mm && rank < K_) {
                const int bpos = __ffsll((long long)mm) - 1;
                mm &= mm - 1;
                sidx[rank++] = (4 * lane + j) * 64 + bpos;
            }
        }
    }
    __syncthreads();

    // pad trailing slots with the first neighbor (reference semantics);
    // found==0 -> JAX OOB gather clamps index N -> N-1.
    const int found = (total < K_) ? total : K_;
    const int first = (found > 0) ? sidx[0] : (N_ - 1);
    if (tid < K_ && tid >= found) sidx[tid] = first;
    __syncthreads();

    // ---- gather + write: 1120 floats, coalesced ----
    float* __restrict__ ob = out + (size_t)q * (K_ * CH_);
    for (int t = tid; t < K_ * CH_; t += 1024) {
        const int k = t / CH_;
        const int c = t - k * CH_;
        const int n = sidx[k];
        ob[t] = (c < 3) ? xb[n * 3 + c] * 0.5f
                        : fb[(size_t)n * F_ + (c - 3)];
    }
}

extern "C" void kernel_launch(void* const* d_in, const int* in_sizes, int n_in,
                              void* d_out, int out_size, void* d_ws, size_t ws_size,
                              hipStream_t stream) {
    const float* cand = (const float*)d_in[0];   // candidate_pts
    // d_in[1] = src_keypts — unused by the reference
    const float* xyz  = (const float*)d_in[2];   // tgt_pts_xyz
    const float* feat = (const float*)d_in[3];   // tgt_deep_feat_pts
    float* out = (float*)d_out;

    ballquery_gather<<<B_ * S_, 1024, 0, stream>>>(cand, xyz, feat, out);
}